// Round 10
// baseline (424.316 us; speedup 1.0000x reference)
//
#include <hip/hip_runtime.h>
#include <hip/hip_bf16.h>

// ---- MoE top-2 fused FFN, bf16 MFMA path ------------------------------------
constexpr int D_    = 512;
constexpr int H_    = 1024;
constexpr int E_    = 8;
constexpr int NTOK_ = 16384;     // B*T = 8*2048
constexpr int MT_   = 64;        // tokens per FFN block tile
constexpr float NEG_ = 0.01f;    // leaky relu slope

typedef short s16x8 __attribute__((ext_vector_type(8)));
typedef float f32x4 __attribute__((ext_vector_type(4)));

#define MFMA16(a,b,c) __builtin_amdgcn_mfma_f32_16x16x32_bf16((a),(b),(c),0,0,0)

__device__ __forceinline__ unsigned short f2bf(float f) {
  unsigned u = __float_as_uint(f);
  u += 0x7FFFu + ((u >> 16) & 1u);       // RNE
  return (unsigned short)(u >> 16);
}
__device__ __forceinline__ float bf2f(unsigned u16) {
  return __uint_as_float(u16 << 16);
}
__device__ __forceinline__ float leaky(float v) {
  return v > 0.f ? v : NEG_ * v;
}

// ---------------------------------------------------------------------------
// 1) prep = router (blocks 0..255) + weight convert (blocks 256..2303), fused.
// Router writes: bf16 x copy (the two 8MB gaps), per-expert inverse map
// tokOfPosE[e][slot]=token, and NOW ALSO wOfPosE[e][slot]=router weight --
// ffn accumulates its weighted output directly into out via atomics, so the
// combine kernel (buf round-trip: 32MB store + 64MB read + 32MB write) is
// deleted from the critical path.
__global__ __launch_bounds__(256) void prep_kernel(
    const float* __restrict__ x, const float* __restrict__ Wr,
    const float* __restrict__ br,
    const float* __restrict__ W1, const float* __restrict__ W2,
    unsigned short* __restrict__ W1s, unsigned short* __restrict__ W2s,
    unsigned short* __restrict__ xbf1, unsigned short* __restrict__ xbf2,
    int* __restrict__ cnt, float* __restrict__ psum,
    int* __restrict__ tokOfPosE, float* __restrict__ wOfPosE) {
  const int blk = blockIdx.x;
  const int tid = threadIdx.x;
  __shared__ float SH[8256 + 32];
  if (blk < 256) {
    // ---------------- router: 64 tokens/block, x staged in padded LDS ------
    const int t0 = blk * 64;
    // no block straddles the 8192 row split (8192 = 128 * 64)
    unsigned short* xbf = (t0 < 8192) ? xbf1 + (size_t)t0 * D_
                                      : xbf2 + (size_t)(t0 - 8192) * D_;
    float* xt   = SH;                        // [64][129]
    float* red  = SH;                        // [256][8] (aliases xt, after barrier)
    float* lp   = SH + 8256;                 // 8
    int*  lcnt  = (int*)(SH + 8256 + 8);     // 8
    int*  gbase = (int*)(SH + 8256 + 16);    // 8
    if (tid < 8) { lcnt[tid] = 0; lp[tid] = 0.f; }

    const int tq = tid & 63;      // token within block
    const int q  = tid >> 6;      // wave = D-quarter
    float acc[E_];
#pragma unroll
    for (int e = 0; e < E_; e++) acc[e] = 0.f;

    for (int c = 0; c < 4; c++) {            // 4 chunks of 128 d's
      __syncthreads();                       // prev consume done (+ init visible)
#pragma unroll
      for (int it = 0; it < 8; it++) {       // stage 64x128 fp32, coalesced
        int f = it * 256 + tid;
        int row = f >> 5, c4 = f & 31;
        float4 v = *(const float4*)(x + (size_t)(t0 + row) * D_ + c * 128 + c4 * 4);
        float* d = xt + row * 129 + c4 * 4;
        d[0] = v.x; d[1] = v.y; d[2] = v.z; d[3] = v.w;
        ushort4 pk;                          // bf16 x copy, coalesced 8B store
        pk.x = f2bf(v.x); pk.y = f2bf(v.y);
        pk.z = f2bf(v.z); pk.w = f2bf(v.w);
        *(ushort4*)(xbf + (size_t)row * D_ + c * 128 + c4 * 4) = pk;
      }
      __syncthreads();
#pragma unroll
      for (int j = 0; j < 32; j++) {
        float xv = xt[tq * 129 + q * 32 + j];                    // bank = tq+j: free
        const float* wr = Wr + (size_t)(c * 128 + q * 32 + j) * E_;  // wave-uniform
#pragma unroll
        for (int e = 0; e < E_; e++) acc[e] += xv * wr[e];
      }
    }
    __syncthreads();              // xt reads done before red overlays it
#pragma unroll
    for (int e = 0; e < E_; e++) red[(q * 64 + tq) * 8 + e] = acc[e];
    __syncthreads();

    float m1 = -1.f, m2 = -1.f; int i1 = 0, i2 = 0, s1 = 0, s2 = 0;
    if (tid < 64) {
      float p[E_];
#pragma unroll
      for (int e = 0; e < E_; e++)
        p[e] = br[e] + red[tid * 8 + e] + red[(64 + tid) * 8 + e]
             + red[(128 + tid) * 8 + e] + red[(192 + tid) * 8 + e];
      float mx = p[0];
#pragma unroll
      for (int e = 1; e < E_; e++) mx = fmaxf(mx, p[e]);
      float s = 0.f;
#pragma unroll
      for (int e = 0; e < E_; e++) { p[e] = expf(p[e] - mx); s += p[e]; }
      float inv = 1.f / s;
#pragma unroll
      for (int e = 0; e < E_; e++) p[e] *= inv;

      // top-2 (strict > keeps lower index on ties, matching jax.lax.top_k)
#pragma unroll
      for (int e = 0; e < E_; e++) {
        float pe = p[e];
        if (pe > m1)      { m2 = m1; i2 = i1; m1 = pe; i1 = e; }
        else if (pe > m2) { m2 = pe; i2 = e; }
      }
      s1 = atomicAdd(&lcnt[i1], 1);
      s2 = atomicAdd(&lcnt[i2], 1);
#pragma unroll
      for (int e = 0; e < E_; e++) atomicAdd(&lp[e], p[e]);
    }
    __syncthreads();
    if (tid < 8) {
      gbase[tid] = atomicAdd(&cnt[tid * 16], lcnt[tid]);  // stride-16: own line
      atomicAdd(&psum[tid * 16], lp[tid]);
    }
    __syncthreads();
    if (tid < 64) {
      int gt = t0 + tid;
      int sl1 = gbase[i1] + s1, sl2 = gbase[i2] + s2;
      tokOfPosE[i1 * NTOK_ + sl1] = gt;      // per-expert inverse map
      tokOfPosE[i2 * NTOK_ + sl2] = gt;
      wOfPosE[i1 * NTOK_ + sl1] = m1;        // per-position router weight
      wOfPosE[i2 * NTOK_ + sl2] = m2;
    }
  } else {
    // ---------------- weight convert (LDS transpose, 16x16 frag layout) ----
    float* ldsf = SH;                 // [64][68] linear
    int bid = blk - 256;              // 0..2047; <1024 -> W1, else W2
    const float* src;
    int eE, kt, tc, srcStride;
    bool isW1 = bid < 1024;
    if (isW1) {
      eE = bid >> 7; kt = (bid >> 4) & 7; tc = bid & 15; srcStride = 1024;
      src = W1 + ((size_t)(eE * 512 + kt * 64)) * 1024 + tc * 64;
    } else {
      int b2i = bid - 1024;
      eE = b2i >> 7; kt = (b2i >> 3) & 15; tc = b2i & 7; srcStride = 512;
      src = W2 + ((size_t)(eE * 1024 + kt * 64)) * 512 + tc * 64;
    }
#pragma unroll
    for (int rep = 0; rep < 4; rep++) {
      int row = rep * 16 + (tid >> 4);
      int c4  = (tid & 15) * 4;
      float4 v = *(const float4*)(src + (size_t)row * srcStride + c4);
      float* d = ldsf + row * 68 + c4;
      d[0] = v.x; d[1] = v.y; d[2] = v.z; d[3] = v.w;
    }
    __syncthreads();
    int wv = tid >> 6, lane = tid & 63;
#pragma unroll
    for (int qi = 0; qi < 2; qi++) {
      int qq = wv * 2 + qi;
      int ks = qq >> 2, nt = qq & 3;
      int k0 = ks * 32 + (lane >> 4) * 8;
      int n  = nt * 16 + (lane & 15);
      s16x8 v;
#pragma unroll
      for (int j = 0; j < 8; j++) v[j] = (short)f2bf(ldsf[(k0 + j) * 68 + n]);
      int ntg = tc * 4 + nt, kkg = kt * 2 + ks;
      if (isW1)
        *(s16x8*)(W1s + (((size_t)eE << 16) + (ntg << 10) + (kkg << 6) + lane) * 8) = v;
      else
        *(s16x8*)(W2s + (((size_t)eE << 16) + (ntg << 11) + (kkg << 6) + lane) * 8) = v;
    }
  }
}

// ---------------------------------------------------------------------------
// 2) Fused two-layer expert FFN: EXACT r9 structure (proven 108us, VGPR 128,
// no spills) with ONLY the epilogue changed: instead of bf16 stores to buf,
// each lane atomically adds w * leaky(acc + bias) (full f32 -- numerics
// improve) into out. out is zeroed by a memset graph node before prep, so
// the two routed experts' adds per (token,col) compose to the reference sum.
// Block 0 writes the balancing loss (psum complete after prep).
__global__ __launch_bounds__(512, 2) void ffn_kernel(
    const unsigned short* __restrict__ xbf1, const unsigned short* __restrict__ xbf2,
    const unsigned short* __restrict__ W1s, const unsigned short* __restrict__ W2s,
    const float* __restrict__ b1, const float* __restrict__ b2,
    const int* __restrict__ cnt, const float* __restrict__ psum,
    const int* __restrict__ tokOfPosE, const float* __restrict__ wOfPosE,
    float* __restrict__ out) {
  if (blockIdx.x == 0 && threadIdx.x == 0) {   // loss (before any early-exit)
    float l = 0.f;
#pragma unroll
    for (int i = 0; i < E_; i++) {
      float d = 0.125f - psum[i * 16] / (float)NTOK_;
      l += d * d;
    }
    out[(size_t)NTOK_ * D_] = (l / 8.f) * 1e-4f;
  }
  const int e = blockIdx.x & 7;          // expert == XCD id -> L2-resident weights
  const int tile = blockIdx.x >> 3;
  int nTok = 0, base0 = 0;
#pragma unroll
  for (int i = 0; i < E_; i++) {
    int ci = cnt[i * 16];
    if (i < e) base0 += ci;
    if (i == e) nTok = ci;
  }
  const int start = tile * MT_;
  if (start >= nTok) return;
  const int valid = min(MT_, nTok - start);

  // one arena, two phases: x tile [64][0..512) bf16, then h tile [64][0..1024).
  __shared__ __align__(16) unsigned short L[MT_][1032];   // 129 KB -> 1 blk/CU

  const int tid = threadIdx.x;
  const int w = tid >> 6;          // 0..7
  const int lane = tid & 63;

  // stage x tile: pure bf16 vector copy; token index lane-uniform -> s_load
  for (int r = w; r < MT_; r += 8) {
    int tok = tokOfPosE[e * NTOK_ + start + min(r, valid - 1)];
    const unsigned short* srow = (tok < 8192)
        ? xbf1 + (size_t)tok * D_
        : xbf2 + (size_t)(tok - 8192) * D_;
    s16x8 v = *(const s16x8*)(srow + lane * 8);
    *(s16x8*)&L[r][lane * 8] = v;
  }
  __syncthreads();

  const int qm = lane & 15;         // C col = token (swapped layout)
  const int qk = (lane >> 4) * 8;   // k offset within 32-K step
  const int qr = (lane >> 4) * 4;   // C row base = 4 consecutive out-dims

  // ---- GEMM1 (swapped): wave w owns hcols [w*128,+128): ntg = w*8+mi, K=512
  const unsigned short* A1 =
      W1s + (((size_t)e << 16) + ((size_t)(w * 8) << 10) + lane) * 8;
  f32x4 acc1[8][4];
#pragma unroll
  for (int mi = 0; mi < 8; mi++)
#pragma unroll
    for (int ni = 0; ni < 4; ni++) acc1[mi][ni] = {0.f, 0.f, 0.f, 0.f};

  s16x8 a1p[2][8];
#pragma unroll
  for (int s = 0; s < 2; s++)
#pragma unroll
    for (int mi = 0; mi < 8; mi++)
      a1p[s][mi] = *(const s16x8*)(A1 + (size_t)mi * 8192 + s * 512);

#pragma unroll
  for (int kk = 0; kk < 16; kk++) {
    s16x8 bcur[4];
#pragma unroll
    for (int ni = 0; ni < 4; ni++)
      bcur[ni] = *(const s16x8*)&L[ni * 16 + qm][kk * 32 + qk];
    __builtin_amdgcn_s_setprio(1);
#pragma unroll
    for (int mi = 0; mi < 8; mi++)
#pragma unroll
      for (int ni = 0; ni < 4; ni++)
        acc1[mi][ni] = MFMA16(a1p[kk & 1][mi], bcur[ni], acc1[mi][ni]);
    __builtin_amdgcn_s_setprio(0);
    if (kk + 2 < 16) {   // refill AFTER the cluster consumed slot kk&1
#pragma unroll
      for (int mi = 0; mi < 8; mi++)
        a1p[kk & 1][mi] = *(const s16x8*)(A1 + (size_t)mi * 8192 + (kk + 2) * 512);
    }
  }
  __syncthreads();   // all waves done reading x from the arena

  // GEMM2 first weight frags: issue NOW -> latency hides under hs writes+drain
  const unsigned short* A2 =
      W2s + (((size_t)e << 16) + ((size_t)(w * 4) << 11) + lane) * 8;
  s16x8 a2p[2][4];
#pragma unroll
  for (int s = 0; s < 2; s++)
#pragma unroll
    for (int mi = 0; mi < 4; mi++)
      a2p[s][mi] = *(const s16x8*)(A2 + (size_t)mi * 16384 + s * 512);

  // h = leaky(h^T + b1): lane holds 4 consecutive hcols -> packed 8B stores
#pragma unroll
  for (int mi = 0; mi < 8; mi++) {
    int hb = w * 128 + mi * 16 + qr;
    float4 bv = *(const float4*)(b1 + (size_t)e * H_ + hb);
#pragma unroll
    for (int ni = 0; ni < 4; ni++) {
      int tr = ni * 16 + qm;
      ushort4 pk;
      pk.x = f2bf(leaky(acc1[mi][ni][0] + bv.x));
      pk.y = f2bf(leaky(acc1[mi][ni][1] + bv.y));
      pk.z = f2bf(leaky(acc1[mi][ni][2] + bv.z));
      pk.w = f2bf(leaky(acc1[mi][ni][3] + bv.w));
      *(ushort4*)&L[tr][hb] = pk;
    }
  }
  __syncthreads();   // h tile ready

  // ---- GEMM2 (swapped): wave w owns outcols [w*64,+64): ntg = w*4+mi, K=1024
  f32x4 acc2[4][4];
#pragma unroll
  for (int mi = 0; mi < 4; mi++)
#pragma unroll
    for (int ni = 0; ni < 4; ni++) acc2[mi][ni] = {0.f, 0.f, 0.f, 0.f};

#pragma unroll
  for (int kk = 0; kk < 32; kk++) {
    s16x8 bcur[4];
#pragma unroll
    for (int ni = 0; ni < 4; ni++)
      bcur[ni] = *(const s16x8*)&L[ni * 16 + qm][kk * 32 + qk];
    __builtin_amdgcn_s_setprio(1);
#pragma unroll
    for (int mi = 0; mi < 4; mi++)
#pragma unroll
      for (int ni = 0; ni < 4; ni++)
        acc2[mi][ni] = MFMA16(a2p[kk & 1][mi], bcur[ni], acc2[mi][ni]);
    __builtin_amdgcn_s_setprio(0);
    if (kk + 2 < 32) {   // refill AFTER the cluster consumed slot kk&1
#pragma unroll
      for (int mi = 0; mi < 4; mi++)
        a2p[kk & 1][mi] = *(const s16x8*)(A2 + (size_t)mi * 16384 + (kk + 2) * 512);
    }
  }

  // epilogue: per-lane token + weight for the 4 token groups, then
  // atomically add w * leaky(acc + b2) (full f32) into out.
  int tokv[4]; float wv[4];
#pragma unroll
  for (int ni = 0; ni < 4; ni++) {
    int tok = ni * 16 + qm;
    int idx = e * NTOK_ + start + min(tok, valid - 1);
    tokv[ni] = tokOfPosE[idx];
    wv[ni]   = wOfPosE[idx];
  }
#pragma unroll
  for (int mi = 0; mi < 4; mi++) {
    int ob = w * 64 + mi * 16 + qr;
    float4 bv = *(const float4*)(b2 + (size_t)e * D_ + ob);
#pragma unroll
    for (int ni = 0; ni < 4; ni++) {
      int tok = ni * 16 + qm;
      if (tok < valid) {
        float* dst = out + (size_t)tokv[ni] * D_ + ob;
        atomicAdd(dst + 0, wv[ni] * leaky(acc2[mi][ni][0] + bv.x));
        atomicAdd(dst + 1, wv[ni] * leaky(acc2[mi][ni][1] + bv.y));
        atomicAdd(dst + 2, wv[ni] * leaky(acc2[mi][ni][2] + bv.z));
        atomicAdd(dst + 3, wv[ni] * leaky(acc2[mi][ni][3] + bv.w));
      }
    }
  }
}

// ---------------------------------------------------------------------------
extern "C" void kernel_launch(void* const* d_in, const int* in_sizes, int n_in,
                              void* d_out, int out_size, void* d_ws, size_t ws_size,
                              hipStream_t stream) {
  const float* x  = (const float*)d_in[0];
  const float* Wr = (const float*)d_in[1];
  const float* br = (const float*)d_in[2];
  const float* W1 = (const float*)d_in[3];
  const float* b1 = (const float*)d_in[4];
  const float* W2 = (const float*)d_in[5];
  const float* b2 = (const float*)d_in[6];
  float* out = (float*)d_out;

  // workspace layout:
  //   [1MB,  9MB)  W1s (8MB)      [9MB, 17MB)  xbf1 (8MB, x rows 0..8191 bf16)
  //   [17MB, 25MB) W2s (8MB)      [25MB, 33MB) xbf2 (8MB, x rows 8192..16383)
  //   [33MB, +512KB) wOfPosE
  char* ws = (char*)d_ws;
  int*   cnt      = (int*)(ws + 0);        // 8 counters, stride 16 ints [zeroed]
  float* psum     = (float*)(ws + 512);    // 8 sums, stride 16 floats  [zeroed]
  int*   tokOfPosE= (int*)(ws + 4096);                       // 512 KB (8 x 16384)
  unsigned short* W1s  = (unsigned short*)(ws + (size_t)(1u << 20));
  unsigned short* xbf1 = (unsigned short*)(ws + (size_t)(1u << 20) + 8388608u);
  unsigned short* W2s  = (unsigned short*)(ws + (size_t)(1u << 20) + 16777216u);
  unsigned short* xbf2 = (unsigned short*)(ws + (size_t)(1u << 20) + 25165824u);
  float* wOfPosE  = (float*)(ws + (size_t)(1u << 20) + 33554432u);       // 512 KB

  hipMemsetAsync(d_ws, 0, 2048, stream);
  // out must be zero before ffn's atomic accumulation (self-contained:
  // no reliance on harness out-reset semantics). Covers output + loss slot.
  hipMemsetAsync(d_out, 0, ((size_t)NTOK_ * D_ + 1) * sizeof(float), stream);
  prep_kernel<<<256 + 2048, 256, 0, stream>>>(x, Wr, br, W1, W2, W1s, W2s,
                                              xbf1, xbf2, cnt, psum,
                                              tokOfPosE, wOfPosE);
  // worst case: every token routes to one expert -> 256 tiles/expert
  ffn_kernel<<<(NTOK_ / MT_) * E_, 512, 0, stream>>>(xbf1, xbf2, W1s, W2s,
                                                     b1, b2, cnt, psum,
                                                     tokOfPosE, wOfPosE, out);
}

// Round 13
// 251.990 us; speedup vs baseline: 1.6839x; 1.6839x over previous
//
#include <hip/hip_runtime.h>
#include <hip/hip_bf16.h>

// ---- MoE top-2 fused FFN, bf16 MFMA path ------------------------------------
constexpr int D_    = 512;
constexpr int H_    = 1024;
constexpr int E_    = 8;
constexpr int NTOK_ = 16384;     // B*T = 8*2048
constexpr int MT_   = 64;        // tokens per FFN block tile
constexpr float NEG_ = 0.01f;    // leaky relu slope

typedef short s16x8 __attribute__((ext_vector_type(8)));
typedef float f32x4 __attribute__((ext_vector_type(4)));

#define MFMA16(a,b,c) __builtin_amdgcn_mfma_f32_16x16x32_bf16((a),(b),(c),0,0,0)

__device__ __forceinline__ unsigned short f2bf(float f) {
  unsigned u = __float_as_uint(f);
  u += 0x7FFFu + ((u >> 16) & 1u);       // RNE
  return (unsigned short)(u >> 16);
}
__device__ __forceinline__ float bf2f(unsigned u16) {
  return __uint_as_float(u16 << 16);
}
__device__ __forceinline__ float leaky(float v) {
  return v > 0.f ? v : NEG_ * v;
}

// ---------------------------------------------------------------------------
// 1) prep = router (blocks 0..255) + weight convert (blocks 256..2303), fused.
// Router writes a bf16 copy of x (the two 8MB gaps after W1s/W2s) and the
// per-expert inverse map tokOfPosE[e][slot]=token. (r10 note: do NOT replace
// the combine stage with f32 global atomics -- measured 262MB HBM write-through,
// ffn 108->288us.)
__global__ __launch_bounds__(256) void prep_kernel(
    const float* __restrict__ x, const float* __restrict__ Wr,
    const float* __restrict__ br,
    const float* __restrict__ W1, const float* __restrict__ W2,
    unsigned short* __restrict__ W1s, unsigned short* __restrict__ W2s,
    unsigned short* __restrict__ xbf1, unsigned short* __restrict__ xbf2,
    int* __restrict__ cnt, float* __restrict__ psum,
    int* __restrict__ tokE, int* __restrict__ tokSlot, float* __restrict__ tokW,
    int* __restrict__ tokOfPosE) {
  const int blk = blockIdx.x;
  const int tid = threadIdx.x;
  __shared__ float SH[8256 + 32];
  if (blk < 256) {
    // ---------------- router: 64 tokens/block, x staged in padded LDS ------
    const int t0 = blk * 64;
    // no block straddles the 8192 row split (8192 = 128 * 64)
    unsigned short* xbf = (t0 < 8192) ? xbf1 + (size_t)t0 * D_
                                      : xbf2 + (size_t)(t0 - 8192) * D_;
    float* xt   = SH;                        // [64][129]
    float* red  = SH;                        // [256][8] (aliases xt, after barrier)
    float* lp   = SH + 8256;                 // 8
    int*  lcnt  = (int*)(SH + 8256 + 8);     // 8
    int*  gbase = (int*)(SH + 8256 + 16);    // 8
    if (tid < 8) { lcnt[tid] = 0; lp[tid] = 0.f; }

    const int tq = tid & 63;      // token within block
    const int q  = tid >> 6;      // wave = D-quarter
    float acc[E_];
#pragma unroll
    for (int e = 0; e < E_; e++) acc[e] = 0.f;

    for (int c = 0; c < 4; c++) {            // 4 chunks of 128 d's
      __syncthreads();                       // prev consume done (+ init visible)
#pragma unroll
      for (int it = 0; it < 8; it++) {       // stage 64x128 fp32, coalesced
        int f = it * 256 + tid;
        int row = f >> 5, c4 = f & 31;
        float4 v = *(const float4*)(x + (size_t)(t0 + row) * D_ + c * 128 + c4 * 4);
        float* d = xt + row * 129 + c4 * 4;
        d[0] = v.x; d[1] = v.y; d[2] = v.z; d[3] = v.w;
        ushort4 pk;                          // bf16 x copy, coalesced 8B store
        pk.x = f2bf(v.x); pk.y = f2bf(v.y);
        pk.z = f2bf(v.z); pk.w = f2bf(v.w);
        *(ushort4*)(xbf + (size_t)row * D_ + c * 128 + c4 * 4) = pk;
      }
      __syncthreads();
#pragma unroll
      for (int j = 0; j < 32; j++) {
        float xv = xt[tq * 129 + q * 32 + j];                    // bank = tq+j: free
        const float* wr = Wr + (size_t)(c * 128 + q * 32 + j) * E_;  // wave-uniform
#pragma unroll
        for (int e = 0; e < E_; e++) acc[e] += xv * wr[e];
      }
    }
    __syncthreads();              // xt reads done before red overlays it
#pragma unroll
    for (int e = 0; e < E_; e++) red[(q * 64 + tq) * 8 + e] = acc[e];
    __syncthreads();

    float m1 = -1.f, m2 = -1.f; int i1 = 0, i2 = 0, s1 = 0, s2 = 0;
    if (tid < 64) {
      float p[E_];
#pragma unroll
      for (int e = 0; e < E_; e++)
        p[e] = br[e] + red[tid * 8 + e] + red[(64 + tid) * 8 + e]
             + red[(128 + tid) * 8 + e] + red[(192 + tid) * 8 + e];
      float mx = p[0];
#pragma unroll
      for (int e = 1; e < E_; e++) mx = fmaxf(mx, p[e]);
      float s = 0.f;
#pragma unroll
      for (int e = 0; e < E_; e++) { p[e] = expf(p[e] - mx); s += p[e]; }
      float inv = 1.f / s;
#pragma unroll
      for (int e = 0; e < E_; e++) p[e] *= inv;

      // top-2 (strict > keeps lower index on ties, matching jax.lax.top_k)
#pragma unroll
      for (int e = 0; e < E_; e++) {
        float pe = p[e];
        if (pe > m1)      { m2 = m1; i2 = i1; m1 = pe; i1 = e; }
        else if (pe > m2) { m2 = pe; i2 = e; }
      }
      s1 = atomicAdd(&lcnt[i1], 1);
      s2 = atomicAdd(&lcnt[i2], 1);
#pragma unroll
      for (int e = 0; e < E_; e++) atomicAdd(&lp[e], p[e]);
    }
    __syncthreads();
    if (tid < 8) {
      gbase[tid] = atomicAdd(&cnt[tid * 16], lcnt[tid]);  // stride-16: own line
      atomicAdd(&psum[tid * 16], lp[tid]);
    }
    __syncthreads();
    if (tid < 64) {
      int gt = t0 + tid;
      int sl1 = gbase[i1] + s1, sl2 = gbase[i2] + s2;
      tokE[2 * gt]     = i1; tokSlot[2 * gt]     = sl1; tokW[2 * gt]     = m1;
      tokE[2 * gt + 1] = i2; tokSlot[2 * gt + 1] = sl2; tokW[2 * gt + 1] = m2;
      tokOfPosE[i1 * NTOK_ + sl1] = gt;      // per-expert inverse map
      tokOfPosE[i2 * NTOK_ + sl2] = gt;
    }
  } else {
    // ---------------- weight convert (LDS transpose, 16x16 frag layout) ----
    float* ldsf = SH;                 // [64][68] linear
    int bid = blk - 256;              // 0..2047; <1024 -> W1, else W2
    const float* src;
    int eE, kt, tc, srcStride;
    bool isW1 = bid < 1024;
    if (isW1) {
      eE = bid >> 7; kt = (bid >> 4) & 7; tc = bid & 15; srcStride = 1024;
      src = W1 + ((size_t)(eE * 512 + kt * 64)) * 1024 + tc * 64;
    } else {
      int b2i = bid - 1024;
      eE = b2i >> 7; kt = (b2i >> 3) & 15; tc = b2i & 7; srcStride = 512;
      src = W2 + ((size_t)(eE * 1024 + kt * 64)) * 512 + tc * 64;
    }
#pragma unroll
    for (int rep = 0; rep < 4; rep++) {
      int row = rep * 16 + (tid >> 4);
      int c4  = (tid & 15) * 4;
      float4 v = *(const float4*)(src + (size_t)row * srcStride + c4);
      float* d = ldsf + row * 68 + c4;
      d[0] = v.x; d[1] = v.y; d[2] = v.z; d[3] = v.w;
    }
    __syncthreads();
    int wv = tid >> 6, lane = tid & 63;
#pragma unroll
    for (int qi = 0; qi < 2; qi++) {
      int qq = wv * 2 + qi;
      int ks = qq >> 2, nt = qq & 3;
      int k0 = ks * 32 + (lane >> 4) * 8;
      int n  = nt * 16 + (lane & 15);
      s16x8 v;
#pragma unroll
      for (int j = 0; j < 8; j++) v[j] = (short)f2bf(ldsf[(k0 + j) * 68 + n]);
      int ntg = tc * 4 + nt, kkg = kt * 2 + ks;
      if (isW1)
        *(s16x8*)(W1s + (((size_t)eE << 16) + (ntg << 10) + (kkg << 6) + lane) * 8) = v;
      else
        *(s16x8*)(W2s + (((size_t)eE << 16) + (ntg << 11) + (kkg << 6) + lane) * 8) = v;
    }
  }
}

// ---------------------------------------------------------------------------
// 2) Fused two-layer expert FFN: r9 structure (proven 108us, VGPR 128, no
// spills) with ONE isolated change: the GEMM1 a1p prologue (16 SGPR-addressed
// weight loads) is issued BEFORE the x-staging loop. The staging barrier's
// mandatory vmcnt(0) drain completes them for free -> cluster 0 no longer
// stalls ~200-400cyc on L2. (Isolates r8's change (b); setprio kept -- r8
// showed the intrinsics double as scheduling fences protecting the register
// budget.)
__global__ __launch_bounds__(512, 2) void ffn_kernel(
    const unsigned short* __restrict__ xbf1, const unsigned short* __restrict__ xbf2,
    const unsigned short* __restrict__ W1s, const unsigned short* __restrict__ W2s,
    const float* __restrict__ b1, const float* __restrict__ b2,
    const int* __restrict__ cnt, const int* __restrict__ tokOfPosE,
    unsigned short* __restrict__ buf) {
  const int e = blockIdx.x & 7;          // expert == XCD id -> L2-resident weights
  const int tile = blockIdx.x >> 3;
  int nTok = 0, base0 = 0;
#pragma unroll
  for (int i = 0; i < E_; i++) {
    int ci = cnt[i * 16];
    if (i < e) base0 += ci;
    if (i == e) nTok = ci;
  }
  const int start = tile * MT_;
  if (start >= nTok) return;
  const int valid = min(MT_, nTok - start);
  const int base = base0 + start;

  // one arena, two phases: x tile [64][0..512) bf16, then h tile [64][0..1024).
  __shared__ __align__(16) unsigned short L[MT_][1032];   // 129 KB -> 1 blk/CU

  const int tid = threadIdx.x;
  const int w = tid >> 6;          // 0..7
  const int lane = tid & 63;

  // GEMM1 prologue FIRST (SGPR-addressed, no LDS dependence): latency hides
  // under x staging; the staging barrier's vmcnt(0) drain completes them.
  const unsigned short* A1 =
      W1s + (((size_t)e << 16) + ((size_t)(w * 8) << 10) + lane) * 8;
  s16x8 a1p[2][8];
#pragma unroll
  for (int s = 0; s < 2; s++)
#pragma unroll
    for (int mi = 0; mi < 8; mi++)
      a1p[s][mi] = *(const s16x8*)(A1 + (size_t)mi * 8192 + s * 512);

  // stage x tile: pure bf16 vector copy; token index lane-uniform -> s_load
  for (int r = w; r < MT_; r += 8) {
    int tok = tokOfPosE[e * NTOK_ + start + min(r, valid - 1)];
    const unsigned short* srow = (tok < 8192)
        ? xbf1 + (size_t)tok * D_
        : xbf2 + (size_t)(tok - 8192) * D_;
    s16x8 v = *(const s16x8*)(srow + lane * 8);
    *(s16x8*)&L[r][lane * 8] = v;
  }
  __syncthreads();

  const int qm = lane & 15;         // C col = token (swapped layout)
  const int qk = (lane >> 4) * 8;   // k offset within 32-K step
  const int qr = (lane >> 4) * 4;   // C row base = 4 consecutive out-dims

  // ---- GEMM1 (swapped): wave w owns hcols [w*128,+128): ntg = w*8+mi, K=512
  f32x4 acc1[8][4];
#pragma unroll
  for (int mi = 0; mi < 8; mi++)
#pragma unroll
    for (int ni = 0; ni < 4; ni++) acc1[mi][ni] = {0.f, 0.f, 0.f, 0.f};

#pragma unroll
  for (int kk = 0; kk < 16; kk++) {
    s16x8 bcur[4];
#pragma unroll
    for (int ni = 0; ni < 4; ni++)
      bcur[ni] = *(const s16x8*)&L[ni * 16 + qm][kk * 32 + qk];
    __builtin_amdgcn_s_setprio(1);
#pragma unroll
    for (int mi = 0; mi < 8; mi++)
#pragma unroll
      for (int ni = 0; ni < 4; ni++)
        acc1[mi][ni] = MFMA16(a1p[kk & 1][mi], bcur[ni], acc1[mi][ni]);
    __builtin_amdgcn_s_setprio(0);
    if (kk + 2 < 16) {   // refill AFTER the cluster consumed slot kk&1
#pragma unroll
      for (int mi = 0; mi < 8; mi++)
        a1p[kk & 1][mi] = *(const s16x8*)(A1 + (size_t)mi * 8192 + (kk + 2) * 512);
    }
  }
  __syncthreads();   // all waves done reading x from the arena

  // GEMM2 first weight frags: issue NOW -> latency hides under hs writes+drain
  const unsigned short* A2 =
      W2s + (((size_t)e << 16) + ((size_t)(w * 4) << 11) + lane) * 8;
  s16x8 a2p[2][4];
#pragma unroll
  for (int s = 0; s < 2; s++)
#pragma unroll
    for (int mi = 0; mi < 4; mi++)
      a2p[s][mi] = *(const s16x8*)(A2 + (size_t)mi * 16384 + s * 512);

  // h = leaky(h^T + b1): lane holds 4 consecutive hcols -> packed 8B stores
#pragma unroll
  for (int mi = 0; mi < 8; mi++) {
    int hb = w * 128 + mi * 16 + qr;
    float4 bv = *(const float4*)(b1 + (size_t)e * H_ + hb);
#pragma unroll
    for (int ni = 0; ni < 4; ni++) {
      int tr = ni * 16 + qm;
      ushort4 pk;
      pk.x = f2bf(leaky(acc1[mi][ni][0] + bv.x));
      pk.y = f2bf(leaky(acc1[mi][ni][1] + bv.y));
      pk.z = f2bf(leaky(acc1[mi][ni][2] + bv.z));
      pk.w = f2bf(leaky(acc1[mi][ni][3] + bv.w));
      *(ushort4*)&L[tr][hb] = pk;
    }
  }
  __syncthreads();   // h tile ready

  // ---- GEMM2 (swapped): wave w owns outcols [w*64,+64): ntg = w*4+mi, K=1024
  f32x4 acc2[4][4];
#pragma unroll
  for (int mi = 0; mi < 4; mi++)
#pragma unroll
    for (int ni = 0; ni < 4; ni++) acc2[mi][ni] = {0.f, 0.f, 0.f, 0.f};

#pragma unroll
  for (int kk = 0; kk < 32; kk++) {
    s16x8 bcur[4];
#pragma unroll
    for (int ni = 0; ni < 4; ni++)
      bcur[ni] = *(const s16x8*)&L[ni * 16 + qm][kk * 32 + qk];
    __builtin_amdgcn_s_setprio(1);
#pragma unroll
    for (int mi = 0; mi < 4; mi++)
#pragma unroll
      for (int ni = 0; ni < 4; ni++)
        acc2[mi][ni] = MFMA16(a2p[kk & 1][mi], bcur[ni], acc2[mi][ni]);
    __builtin_amdgcn_s_setprio(0);
    if (kk + 2 < 32) {   // refill AFTER the cluster consumed slot kk&1
#pragma unroll
      for (int mi = 0; mi < 4; mi++)
        a2p[kk & 1][mi] = *(const s16x8*)(A2 + (size_t)mi * 16384 + (kk + 2) * 512);
    }
  }

  // epilogue: out^T -> pack 4 consecutive outcols -> 8B global stores
#pragma unroll
  for (int mi = 0; mi < 4; mi++) {
    int ob = w * 64 + mi * 16 + qr;
    float4 bv = *(const float4*)(b2 + (size_t)e * D_ + ob);
#pragma unroll
    for (int ni = 0; ni < 4; ni++) {
      int tok = ni * 16 + qm;
      if (tok < valid) {
        ushort4 pk;
        pk.x = f2bf(leaky(acc2[mi][ni][0] + bv.x));
        pk.y = f2bf(leaky(acc2[mi][ni][1] + bv.y));
        pk.z = f2bf(leaky(acc2[mi][ni][2] + bv.z));
        pk.w = f2bf(leaky(acc2[mi][ni][3] + bv.w));
        *(ushort4*)(buf + (size_t)(base + tok) * D_ + ob) = pk;
      }
    }
  }
}

// 3) out[t] = w0*buf[pos0] + w1*buf[pos1]; one wave per token, uint4 loads.
// Computes the expert prefix from cnt itself and block 0 writes the loss.
__global__ __launch_bounds__(256) void combine_kernel(
    const unsigned short* __restrict__ buf,
    const int* __restrict__ tokE, const int* __restrict__ tokSlot,
    const float* __restrict__ tokW,
    const int* __restrict__ cnt, const float* __restrict__ psum,
    float* __restrict__ out, float* __restrict__ loss_out) {
  __shared__ int soff[E_];
  if (threadIdx.x == 0) {
    int o = 0;
#pragma unroll
    for (int e = 0; e < E_; e++) { soff[e] = o; o += cnt[e * 16]; }
  }
  __syncthreads();
  if (blockIdx.x == 0 && threadIdx.x == 0) {
    float l = 0.f;
#pragma unroll
    for (int e = 0; e < E_; e++) {
      float d = 0.125f - psum[e * 16] / (float)NTOK_;
      l += d * d;
    }
    *loss_out = (l / 8.f) * 1e-4f;
  }
  int t = blockIdx.x * 4 + (threadIdx.x >> 6);
  int lane = threadIdx.x & 63;
  int p0 = soff[tokE[2 * t]]     + tokSlot[2 * t];       // lane-uniform
  int p1 = soff[tokE[2 * t + 1]] + tokSlot[2 * t + 1];
  float w0 = tokW[2 * t], w1 = tokW[2 * t + 1];
  uint4 u0 = ((const uint4*)(buf + (size_t)p0 * D_))[lane];
  uint4 u1 = ((const uint4*)(buf + (size_t)p1 * D_))[lane];
  float4 oA, oB;
  oA.x = w0 * bf2f(u0.x & 0xFFFFu) + w1 * bf2f(u1.x & 0xFFFFu);
  oA.y = w0 * bf2f(u0.x >> 16)     + w1 * bf2f(u1.x >> 16);
  oA.z = w0 * bf2f(u0.y & 0xFFFFu) + w1 * bf2f(u1.y & 0xFFFFu);
  oA.w = w0 * bf2f(u0.y >> 16)     + w1 * bf2f(u1.y >> 16);
  oB.x = w0 * bf2f(u0.z & 0xFFFFu) + w1 * bf2f(u1.z & 0xFFFFu);
  oB.y = w0 * bf2f(u0.z >> 16)     + w1 * bf2f(u1.z >> 16);
  oB.z = w0 * bf2f(u0.w & 0xFFFFu) + w1 * bf2f(u1.w & 0xFFFFu);
  oB.w = w0 * bf2f(u0.w >> 16)     + w1 * bf2f(u1.w >> 16);
  float4* dst = (float4*)(out + (size_t)t * D_);
  dst[lane * 2]     = oA;
  dst[lane * 2 + 1] = oB;
}

// ---------------------------------------------------------------------------
extern "C" void kernel_launch(void* const* d_in, const int* in_sizes, int n_in,
                              void* d_out, int out_size, void* d_ws, size_t ws_size,
                              hipStream_t stream) {
  const float* x  = (const float*)d_in[0];
  const float* Wr = (const float*)d_in[1];
  const float* br = (const float*)d_in[2];
  const float* W1 = (const float*)d_in[3];
  const float* b1 = (const float*)d_in[4];
  const float* W2 = (const float*)d_in[5];
  const float* b2 = (const float*)d_in[6];
  float* out = (float*)d_out;

  // workspace layout (span ~66.5MB, proven in rounds 0-9):
  //   [1MB,  9MB)  W1s (8MB)      [9MB, 17MB)  xbf1 (8MB, x rows 0..8191 bf16)
  //   [17MB, 25MB) W2s (8MB)      [25MB, 33MB) xbf2 (8MB, x rows 8192..16383)
  //   [33MB, 65MB) buf (32MB)
  char* ws = (char*)d_ws;
  int*   cnt      = (int*)(ws + 0);        // 8 counters, stride 16 ints [zeroed]
  float* psum     = (float*)(ws + 512);    // 8 sums, stride 16 floats  [zeroed]
  int*   tokE     = (int*)(ws + 4096);                       // 128 KB
  int*   tokSlot  = (int*)(ws + 4096 + 1 * 131072);          // 128 KB
  float* tokW     = (float*)(ws + 4096 + 2 * 131072);        // 128 KB
  int*   tokOfPosE= (int*)(ws + 4096 + 3 * 131072);          // 512 KB (8 x 16384)
  unsigned short* W1s  = (unsigned short*)(ws + (size_t)(1u << 20));
  unsigned short* xbf1 = (unsigned short*)(ws + (size_t)(1u << 20) + 8388608u);
  unsigned short* W2s  = (unsigned short*)(ws + (size_t)(1u << 20) + 16777216u);
  unsigned short* xbf2 = (unsigned short*)(ws + (size_t)(1u << 20) + 25165824u);
  unsigned short* buf  = (unsigned short*)(ws + (size_t)(1u << 20) + 33554432u);

  hipMemsetAsync(d_ws, 0, 2048, stream);
  prep_kernel<<<256 + 2048, 256, 0, stream>>>(x, Wr, br, W1, W2, W1s, W2s,
                                              xbf1, xbf2,
                                              cnt, psum, tokE, tokSlot, tokW,
                                              tokOfPosE);
  // worst case: every token routes to one expert -> 256 tiles/expert
  ffn_kernel<<<(NTOK_ / MT_) * E_, 512, 0, stream>>>(xbf1, xbf2, W1s, W2s,
                                                     b1, b2, cnt, tokOfPosE, buf);
  combine_kernel<<<NTOK_ / 4, 256, 0, stream>>>(buf, tokE, tokSlot, tokW,
                                                cnt, psum, out,
                                                out + (size_t)NTOK_ * D_);
}